// Round 1
// 904.444 us; speedup vs baseline: 1.0810x; 1.0810x over previous
//
#include <hip/hip_runtime.h>
#include <stdint.h>

#define S_TOK 8192
#define HID 2880
#define NQ 64
#define NKV 8
#define HD 64
#define QKV_N 5120   // 4096 q + 512 k + 512 v
#define NO_PAD 2944  // 2880 padded to multiple of 128

typedef __attribute__((ext_vector_type(8))) __bf16 bf16x8;
typedef __attribute__((ext_vector_type(4))) float f32x4;

__device__ __forceinline__ unsigned short f2bf(float f) {
  unsigned int u = __builtin_bit_cast(unsigned int, f);
  u += 0x7fff + ((u >> 16) & 1);
  return (unsigned short)(u >> 16);
}
__device__ __forceinline__ float bf2f(unsigned short h) {
  unsigned int u = ((unsigned int)h) << 16;
  return __builtin_bit_cast(float, u);
}

__device__ __forceinline__ void async_lds16(const void* g, void* l) {
  __builtin_amdgcn_global_load_lds(
      (const __attribute__((address_space(1))) unsigned int*)g,
      (__attribute__((address_space(3))) unsigned int*)l, 16, 0, 0);
}

__device__ __forceinline__ void wg_barrier() {
  asm volatile("" ::: "memory");
  __builtin_amdgcn_s_barrier();
  asm volatile("" ::: "memory");
}

// ---------------- elementwise f32 -> bf16 ----------------
__global__ __launch_bounds__(256) void cvt_bf16_kernel(
    const float* __restrict__ src, unsigned short* __restrict__ dst) {
  size_t i = ((size_t)blockIdx.x * 256 + threadIdx.x) * 8;
  float4 a = *(const float4*)(src + i);
  float4 b = *(const float4*)(src + i + 4);
  union { unsigned short u[8]; uint4 v; } o;
  o.u[0] = f2bf(a.x); o.u[1] = f2bf(a.y); o.u[2] = f2bf(a.z); o.u[3] = f2bf(a.w);
  o.u[4] = f2bf(b.x); o.u[5] = f2bf(b.y); o.u[6] = f2bf(b.z); o.u[7] = f2bf(b.w);
  *(uint4*)(dst + i) = o.v;
}

// ------------- transpose + convert: src[R][C] f32 -> dst[(c+rowOff)][R] bf16 -------------
__global__ __launch_bounds__(256) void transpose_cvt(
    const float* __restrict__ src, unsigned short* __restrict__ dst,
    int R, int C, int rowOff) {
  __shared__ float tile[32][33];
  int tx = threadIdx.x, ty = threadIdx.y;  // block (32,8)
  int c0 = blockIdx.x * 32, r0 = blockIdx.y * 32;
#pragma unroll
  for (int i = 0; i < 4; ++i)
    tile[ty + i * 8][tx] = src[(size_t)(r0 + ty + i * 8) * C + c0 + tx];
  __syncthreads();
#pragma unroll
  for (int i = 0; i < 4; ++i)
    dst[(size_t)(c0 + ty + i * 8 + rowOff) * R + r0 + tx] = f2bf(tile[tx][ty + i * 8]);
}

// ---------------- in-place RoPE on q (heads 0..63) and k (heads 64..71) ----------------
__global__ __launch_bounds__(256) void rope_kernel(
    unsigned short* __restrict__ qkv, const int* __restrict__ positions) {
  int gid = blockIdx.x * 256 + threadIdx.x;   // 8192*72*32 total
  int d = gid & 31;
  int rest = gid >> 5;
  int head = rest % 72;
  int t = rest / 72;
  unsigned short* p = qkv + (size_t)t * QKV_N + head * 64;
  float x1 = bf2f(p[d]);
  float x2 = bf2f(p[d + 32]);
  float pos = (float)positions[t];
  float inv = exp2f(-0.5373313430f * (float)d);
  float ang = pos * inv;
  float s = sinf(ang), c = cosf(ang);
  p[d] = f2bf(x1 * c - x2 * s);
  p[d + 32] = f2bf(x2 * c + x1 * s);
}

// ---------------- 256x128-tile, 3-deep-pipelined bf16 GEMM (T2+T3+T4+T5) ----------------
// 8 waves (2Mx4N), per-wave 128x32 C, 16x16x32 MFMA.
// 3-buffer LDS ring (48KB/K-tile, 144KB): compute tile t, stage tile t+2.
// Counted s_waitcnt vmcnt(6) once per K-tile -- never drains to 0 in main loop.
// XOR swizzle chunk^=(row&7), inverse-applied on the global source address
// (global_load_lds dest must stay linear), re-applied on ds_read.
// MODE 0: bf16 out via LDS repack, 3-segment bias (bq|bk|bv)
// MODE 1: f32 out + bo, valid cols < 2880
template <int MODE>
__global__ __launch_bounds__(512, 2) void gemm256(
    const unsigned short* __restrict__ A, const unsigned short* __restrict__ BT,
    void* __restrict__ Cout, int K, int NT,
    const float* __restrict__ b0, const float* __restrict__ b1,
    const float* __restrict__ b2) {
  __shared__ unsigned short lds[3 * 24576];  // 3 x (A 16384 + B 8192 ushorts) = 144KB
  const int tid = threadIdx.x;
  const int lane = tid & 63;
  const int wid = tid >> 6;
  const int wy = wid >> 2, wx = wid & 3;       // 2 x 4 wave grid
  const int l15 = lane & 15, l4 = lane >> 4;
  const int m0 = blockIdx.y * 256, n0 = blockIdx.x * 128;

  const unsigned short* Ag = A + (size_t)m0 * K;
  const unsigned short* Bg = BT + (size_t)n0 * K;

  f32x4 acc[8][2];
#pragma unroll
  for (int m = 0; m < 8; ++m)
#pragma unroll
    for (int n = 0; n < 2; ++n)
#pragma unroll
      for (int r = 0; r < 4; ++r) acc[m][n][r] = 0.f;

  // stage one K-tile's A (256x64, 4 rounds) / B (128x64, 2 rounds)
  auto stageA = [&](int t, int buf) {
    unsigned short* dst = lds + buf * 24576;
    const unsigned short* G = Ag + t * 64;
#pragma unroll
    for (int rd = 0; rd < 4; ++rd) {
      int s = tid + rd * 512;
      int row = s >> 3;
      int g = (s & 7) ^ (row & 7);    // inverse swizzle on the SOURCE chunk
      async_lds16(G + (size_t)row * K + g * 8, &dst[s * 8]);
    }
  };
  auto stageB = [&](int t, int buf) {
    unsigned short* dst = lds + buf * 24576 + 16384;
    const unsigned short* G = Bg + t * 64;
#pragma unroll
    for (int rd = 0; rd < 2; ++rd) {
      int s = tid + rd * 512;
      int row = s >> 3;
      int g = (s & 7) ^ (row & 7);
      async_lds16(G + (size_t)row * K + g * 8, &dst[s * 8]);
    }
  };

  // prologue: tiles 0 and 1 in flight; wait for tile 0 (6 newest may stay out)
  stageA(0, 0); stageB(0, 0);
  stageA(1, 1); stageB(1, 1);
  asm volatile("s_waitcnt vmcnt(6)" ::: "memory");
  wg_barrier();

  int cur = 0, nxt = 2;
  for (int t = 0; t < NT; ++t) {
    const unsigned short* As = lds + cur * 24576;
    const unsigned short* Bs = As + 16384;
    bf16x8 bfrag[2][2], af0[4][2], af1[4][2];

    // ---- phase 0: read B (all) + A mreps 0..3 ; stage A of tile t+2 ----
#pragma unroll
    for (int n = 0; n < 2; ++n)
#pragma unroll
      for (int ks = 0; ks < 2; ++ks) {
        int row = wx * 32 + n * 16 + l15;
        int ch = (ks * 4 + l4) ^ (row & 7);
        bfrag[n][ks] = *(const bf16x8*)&Bs[row * 64 + ch * 8];
      }
#pragma unroll
    for (int m = 0; m < 4; ++m)
#pragma unroll
      for (int ks = 0; ks < 2; ++ks) {
        int row = wy * 128 + m * 16 + l15;
        int ch = (ks * 4 + l4) ^ (row & 7);
        af0[m][ks] = *(const bf16x8*)&As[row * 64 + ch * 8];
      }
    if (t + 2 < NT) stageA(t + 2, nxt);
    wg_barrier();
    asm volatile("s_waitcnt lgkmcnt(0)" ::: "memory");
    __builtin_amdgcn_sched_barrier(0);
    __builtin_amdgcn_s_setprio(1);
#pragma unroll
    for (int m = 0; m < 4; ++m)
#pragma unroll
      for (int n = 0; n < 2; ++n)
#pragma unroll
        for (int ks = 0; ks < 2; ++ks)
          acc[m][n] = __builtin_amdgcn_mfma_f32_16x16x32_bf16(
              af0[m][ks], bfrag[n][ks], acc[m][n], 0, 0, 0);
    __builtin_amdgcn_s_setprio(0);
    wg_barrier();

    // ---- phase 1: read A mreps 4..7 ; stage B of tile t+2 ----
#pragma unroll
    for (int m = 0; m < 4; ++m)
#pragma unroll
      for (int ks = 0; ks < 2; ++ks) {
        int row = wy * 128 + (m + 4) * 16 + l15;
        int ch = (ks * 4 + l4) ^ (row & 7);
        af1[m][ks] = *(const bf16x8*)&As[row * 64 + ch * 8];
      }
    if (t + 2 < NT) stageB(t + 2, nxt);
    wg_barrier();
    asm volatile("s_waitcnt lgkmcnt(0)" ::: "memory");
    __builtin_amdgcn_sched_barrier(0);
    __builtin_amdgcn_s_setprio(1);
#pragma unroll
    for (int m = 0; m < 4; ++m)
#pragma unroll
      for (int n = 0; n < 2; ++n)
#pragma unroll
        for (int ks = 0; ks < 2; ++ks)
          acc[m + 4][n] = __builtin_amdgcn_mfma_f32_16x16x32_bf16(
              af1[m][ks], bfrag[n][ks], acc[m + 4][n], 0, 0, 0);
    __builtin_amdgcn_s_setprio(0);
    // counted per-tile wait: newest 6 loads (= tile t+2) may stay in flight,
    // everything older (tile t+1) must have landed before next iteration reads it.
    if (t + 2 < NT) { asm volatile("s_waitcnt vmcnt(6)" ::: "memory"); }
    else            { asm volatile("s_waitcnt vmcnt(0)" ::: "memory"); }
    wg_barrier();
    cur = (cur == 2) ? 0 : cur + 1;
    nxt = (nxt == 2) ? 0 : nxt + 1;
  }
  __syncthreads();

  // C/D layout (16x16): col = lane&15, row = (lane>>4)*4 + reg
  if (MODE == 0) {
    unsigned short* ldsC = lds;  // 256 x 136 (padded stride)
#pragma unroll
    for (int n = 0; n < 2; ++n) {
      int col = wx * 32 + n * 16 + l15;
      int gcol = n0 + col;
      float bias = (gcol < 4096) ? b0[gcol]
                                 : (gcol < 4608 ? b1[gcol - 4096] : b2[gcol - 4608]);
#pragma unroll
      for (int m = 0; m < 8; ++m)
#pragma unroll
        for (int r = 0; r < 4; ++r) {
          int row = wy * 128 + m * 16 + l4 * 4 + r;
          ldsC[row * 136 + col] = f2bf(acc[m][n][r] + bias);
        }
    }
    __syncthreads();
    unsigned short* C16 = (unsigned short*)Cout;
#pragma unroll
    for (int i = 0; i < 8; ++i) {  // 8 * 512 thr * 8 elems = full 256x128
      int s = tid + i * 512;
      int row = s >> 4;
      int cc = (s & 15) * 8;
      *(uint4*)(C16 + (size_t)(m0 + row) * QKV_N + n0 + cc) =
          *(const uint4*)&ldsC[row * 136 + cc];
    }
  } else {
    float* Cf = (float*)Cout;
#pragma unroll
    for (int n = 0; n < 2; ++n) {
      int gcol = n0 + wx * 32 + n * 16 + l15;
      if (gcol < HID) {
        float bias = b0[gcol];
#pragma unroll
        for (int m = 0; m < 8; ++m)
#pragma unroll
          for (int r = 0; r < 4; ++r) {
            int row = m0 + wy * 128 + m * 16 + l4 * 4 + r;
            Cf[(size_t)row * HID + gcol] = acc[m][n][r] + bias;
          }
      }
    }
  }
}

// ---------------- sliding-window GQA attention ----------------
// grid (128 q-blocks of 64 rows, 64 heads); block 256
__global__ __launch_bounds__(256) void attn_kernel(
    const unsigned short* __restrict__ qkv, unsigned short* __restrict__ attn) {
  __shared__ unsigned short Qs[64 * 72];    // q rows, stride 72 (pad)
  __shared__ unsigned short Ks[192 * 72];   // ctx keys, stride 72; reused as P[64*200]
  __shared__ unsigned short VTs[64 * 200];  // V transposed: [dim][key], stride 200

  const int tid = threadIdx.x;
  const int B = blockIdx.x;   // 64-row query block
  const int h = blockIdx.y;
  const int hk = h >> 3;
  const int wave = tid >> 6, lane = tid & 63;
  const int quad = lane >> 4, ml = lane & 15;

  // stage Q: 64 rows x 64 cols
#pragma unroll
  for (int it = 0; it < 2; ++it) {
    int s = tid + it * 256;
    int row = s >> 3, c = (s & 7) << 3;
    *(uint4*)&Qs[row * 72 + c] =
        *(const uint4*)(qkv + (size_t)(B * 64 + row) * QKV_N + h * 64 + c);
  }
  // stage K (natural) and V (transposed): 192 ctx rows
#pragma unroll
  for (int it = 0; it < 6; ++it) {
    int s = tid + it * 256;
    int j = s >> 3, c = (s & 7) << 3;
    int tk = B * 64 - 128 + j;
    uint4 kv = make_uint4(0, 0, 0, 0), vv = make_uint4(0, 0, 0, 0);
    if (tk >= 0) {
      kv = *(const uint4*)(qkv + (size_t)tk * QKV_N + 4096 + hk * 64 + c);
      vv = *(const uint4*)(qkv + (size_t)tk * QKV_N + 4608 + hk * 64 + c);
    }
    *(uint4*)&Ks[j * 72 + c] = kv;
    union { uint4 q; unsigned short u[8]; } vu;
    vu.q = vv;
#pragma unroll
    for (int e = 0; e < 8; ++e) VTs[(c + e) * 200 + j] = vu.u[e];
  }
  __syncthreads();

  // scores: wave handles q rows [wave*16, wave*16+16), all 192 ctx cols
  f32x4 zero = {0.f, 0.f, 0.f, 0.f};
  f32x4 sc[12];
#pragma unroll
  for (int jn = 0; jn < 12; ++jn) sc[jn] = zero;
#pragma unroll
  for (int kk = 0; kk < 2; ++kk) {
    bf16x8 af = *(const bf16x8*)&Qs[(wave * 16 + ml) * 72 + kk * 32 + quad * 8];
#pragma unroll
    for (int jn = 0; jn < 12; ++jn) {
      bf16x8 bfr = *(const bf16x8*)&Ks[(jn * 16 + ml) * 72 + kk * 32 + quad * 8];
      sc[jn] = __builtin_amdgcn_mfma_f32_16x16x32_bf16(af, bfr, sc[jn], 0, 0, 0);
    }
  }

  // mask + scale + softmax (rows = wave*16 + quad*4 + r; col = jn*16 + ml)
  const float NEG = -3.0e38f;
  float mx[4], sm[4];
#pragma unroll
  for (int r = 0; r < 4; ++r) mx[r] = NEG;
#pragma unroll
  for (int jn = 0; jn < 12; ++jn) {
    int j = jn * 16 + ml;
#pragma unroll
    for (int r = 0; r < 4; ++r) {
      int i = wave * 16 + quad * 4 + r;
      bool valid = (j > i) && (j <= i + 128) && (B * 64 + j - 128 >= 0);
      float v = valid ? sc[jn][r] * 0.125f : NEG;
      sc[jn][r] = v;
      mx[r] = fmaxf(mx[r], v);
    }
  }
#pragma unroll
  for (int r = 0; r < 4; ++r) {
#pragma unroll
    for (int off = 1; off < 16; off <<= 1)
      mx[r] = fmaxf(mx[r], __shfl_xor(mx[r], off, 64));
    sm[r] = 0.f;
  }
#pragma unroll
  for (int jn = 0; jn < 12; ++jn) {
#pragma unroll
    for (int r = 0; r < 4; ++r) {
      float p = expf(sc[jn][r] - mx[r]);  // masked entries underflow to 0
      sc[jn][r] = p;
      sm[r] += p;
    }
  }
#pragma unroll
  for (int r = 0; r < 4; ++r) {
#pragma unroll
    for (int off = 1; off < 16; off <<= 1) sm[r] += __shfl_xor(sm[r], off, 64);
    sm[r] = 1.0f / sm[r];
  }
  __syncthreads();  // everyone done reading Qs/Ks before P overwrites Ks

  unsigned short* P = Ks;  // overlay: 64 rows, stride 200
#pragma unroll
  for (int jn = 0; jn < 12; ++jn) {
#pragma unroll
    for (int r = 0; r < 4; ++r)
      P[(wave * 16 + quad * 4 + r) * 200 + jn * 16 + ml] = f2bf(sc[jn][r] * sm[r]);
  }
  __syncthreads();

  // PV: O[16 x 64] per wave, K-dim = 192
  f32x4 ov[4];
#pragma unroll
  for (int jn = 0; jn < 4; ++jn) ov[jn] = zero;
#pragma unroll
  for (int ks = 0; ks < 6; ++ks) {
    bf16x8 af = *(const bf16x8*)&P[(wave * 16 + ml) * 200 + ks * 32 + quad * 8];
#pragma unroll
    for (int jn = 0; jn < 4; ++jn) {
      bf16x8 bfr = *(const bf16x8*)&VTs[(jn * 16 + ml) * 200 + ks * 32 + quad * 8];
      ov[jn] = __builtin_amdgcn_mfma_f32_16x16x32_bf16(af, bfr, ov[jn], 0, 0, 0);
    }
  }
#pragma unroll
  for (int jn = 0; jn < 4; ++jn) {
#pragma unroll
    for (int r = 0; r < 4; ++r) {
      int row = B * 64 + wave * 16 + quad * 4 + r;
      attn[(size_t)row * 4096 + h * 64 + jn * 16 + ml] = f2bf(ov[jn][r]);
    }
  }
}

extern "C" void kernel_launch(void* const* d_in, const int* in_sizes, int n_in,
                              void* d_out, int out_size, void* d_ws, size_t ws_size,
                              hipStream_t stream) {
  const float* hidden = (const float*)d_in[0];
  const int* positions = (const int*)d_in[1];
  const float* Wq = (const float*)d_in[2];
  const float* bq = (const float*)d_in[3];
  const float* Wk = (const float*)d_in[4];
  const float* bk = (const float*)d_in[5];
  const float* Wv = (const float*)d_in[6];
  const float* bv = (const float*)d_in[7];
  const float* Wo = (const float*)d_in[8];
  const float* bo = (const float*)d_in[9];
  float* out = (float*)d_out;

  char* ws = (char*)d_ws;
  unsigned short* A_h   = (unsigned short*)(ws);
  unsigned short* BTqkv = (unsigned short*)(ws + 47185920);
  unsigned short* qkv   = (unsigned short*)(ws + 76677120);
  unsigned short* BTo   = (unsigned short*)(ws + 160563200);
  unsigned short* attn  = (unsigned short*)(ws);

  cvt_bf16_kernel<<<11520, 256, 0, stream>>>(hidden, A_h);
  dim3 tb(32, 8);
  transpose_cvt<<<dim3(128, 90), tb, 0, stream>>>(Wq, BTqkv, HID, 4096, 0);
  transpose_cvt<<<dim3(16, 90), tb, 0, stream>>>(Wk, BTqkv, HID, 512, 4096);
  transpose_cvt<<<dim3(16, 90), tb, 0, stream>>>(Wv, BTqkv, HID, 512, 4608);
  transpose_cvt<<<dim3(90, 128), tb, 0, stream>>>(Wo, BTo, 4096, HID, 0);
  hipMemsetAsync(BTo + (size_t)HID * 4096, 0, (size_t)(NO_PAD - HID) * 4096 * 2, stream);

  gemm256<0><<<dim3(QKV_N / 128, S_TOK / 256), 512, 0, stream>>>(
      A_h, BTqkv, qkv, HID, HID / 64, bq, bk, bv);
  rope_kernel<<<73728, 256, 0, stream>>>(qkv, positions);
  attn_kernel<<<dim3(S_TOK / 64, NQ), 256, 0, stream>>>(qkv, attn);
  gemm256<1><<<dim3(NO_PAD / 128, S_TOK / 256), 512, 0, stream>>>(
      attn, BTo, out, 4096, 4096 / 64, bo, nullptr, nullptr);
}